// Round 17
// baseline (273.001 us; speedup 1.0000x reference)
//
#include <hip/hip_runtime.h>
#include <hip/hip_bf16.h>
#include <math.h>

// Problem constants
#define BB 8
#define SS 512
#define DD 768
#define LL 200

typedef __attribute__((ext_vector_type(8))) short bf16x8;
typedef __attribute__((ext_vector_type(4))) float f32x4;

__device__ inline short f2bf(float f) {
    unsigned u = __builtin_bit_cast(unsigned, f);
    unsigned r = (u + 0x7FFFu + ((u >> 16) & 1u)) >> 16;
    return (short)r;
}
__device__ inline float bf2f(short s) {
    unsigned u = ((unsigned)(unsigned short)s) << 16;
    return __builtin_bit_cast(float, u);
}

// ---------------------------------------------------------------------------
// MFMA bf16 GEMM, BK=256 (R14/R15/R16-verified)
// ---------------------------------------------------------------------------
#define LDP3 264   // LDS row pitch (528 B = 33*16B odd)
#define BK3  256
#define MGLDS (2 * 64 * LDP3 * 2)   // 67584 B dynamic

template<int EPI, bool TB>
__global__ __launch_bounds__(256, 1) void mgemm_k(
    const short* __restrict__ A, int lda,
    const void* __restrict__ Bv, int ldb,
    const float* __restrict__ bias,
    const void* __restrict__ Bv2, const float* __restrict__ bias2, int nsplit,
    const void* __restrict__ Bv3, const float* __restrict__ bias3, int nsplit2,
    float* __restrict__ Cf, int ldc,
    short* __restrict__ Cb, int ldcb,
    short* __restrict__ Ct, int ldct, int nsplitT,
    int M, int N, int K)
{
    extern __shared__ short dsm[];
    short* As = dsm;
    short* Bs = dsm + 64 * LDP3;
    const int tid = threadIdx.x;
    const int bm = blockIdx.y * 64;
    const int bn = blockIdx.x * 64;
    int bnb = bn;
    if (!TB) {
        if (bn >= nsplit2)      { Bv = Bv3; bias = bias3; bnb = bn - nsplit2; }
        else if (bn >= nsplit)  { Bv = Bv2; bias = bias2; bnb = bn - nsplit; }
    }
    const int w = tid >> 6, lane = tid & 63, g = lane >> 4, ln = lane & 15;
    const int Kp = (K + BK3 - 1) & ~(BK3 - 1);
    const int nt = Kp >> 8;

    const int ar = tid >> 2, ac = tid & 3;
    const int bn_ = tid & 63, bko = (tid >> 6) * 64;

    f32x4 acc[4];
    #pragma unroll
    for (int i = 0; i < 4; ++i) acc[i] = (f32x4){0.f, 0.f, 0.f, 0.f};

    bf16x8 aR[8], bT[8];
    #pragma unroll
    for (int j = 0; j < 8; ++j) { aR[j] = (bf16x8){0,0,0,0,0,0,0,0}; bT[j] = (bf16x8){0,0,0,0,0,0,0,0}; }
    float bF[64];
    #pragma unroll
    for (int j = 0; j < 64; ++j) bF[j] = 0.f;

    const int gmS = bm + ar;
    const bool aOk = (gmS < M);

    auto fetchA = [&](int k0) {
        if (aOk) {
            const short* p = A + (size_t)gmS * lda + k0 + ac * 64;
            #pragma unroll
            for (int j = 0; j < 8; ++j) aR[j] = *(const bf16x8*)(p + j * 8);
        }
    };
    auto fetchB = [&](int k0) {
        if (TB) {
            const short* Bt = (const short*)Bv;
            int gn = bn + ar;
            if (gn < N) {
                const short* p = Bt + (size_t)gn * ldb + k0 + ac * 64;
                #pragma unroll
                for (int j = 0; j < 8; ++j) bT[j] = *(const bf16x8*)(p + j * 8);
            }
        } else {
            const float* Bp = (const float*)Bv + (size_t)(bnb + bn_);
            #pragma unroll
            for (int j = 0; j < 64; ++j) {
                int gk = k0 + bko + j;
                bF[j] = (gk < K) ? Bp[(size_t)gk * ldb] : 0.f;
            }
        }
    };

    fetchA(0);
    fetchB(0);

    for (int t = 0; t < nt; ++t) {
        {
            short* pa = As + ar * LDP3 + ac * 64;
            #pragma unroll
            for (int j = 0; j < 8; ++j) *(bf16x8*)(pa + j * 8) = aR[j];
        }
        if (TB) {
            short* pb = Bs + ar * LDP3 + ac * 64;
            #pragma unroll
            for (int j = 0; j < 8; ++j) *(bf16x8*)(pb + j * 8) = bT[j];
        } else {
            short* pb = Bs + bn_ * LDP3 + bko;
            #pragma unroll
            for (int q = 0; q < 8; ++q) {
                bf16x8 v;
                #pragma unroll
                for (int e = 0; e < 8; ++e) v[e] = f2bf(bF[q * 8 + e]);
                *(bf16x8*)(pb + q * 8) = v;
            }
        }
        __syncthreads();

        if (t + 1 < nt) {
            int k0 = (t + 1) << 8;
            fetchA(k0);
            fetchB(k0);
        }

        #pragma unroll
        for (int ks = 0; ks < 8; ++ks) {
            bf16x8 a = *(const bf16x8*)(As + (w * 16 + ln) * LDP3 + ks * 32 + g * 8);
            #pragma unroll
            for (int nb = 0; nb < 4; ++nb) {
                bf16x8 b = *(const bf16x8*)(Bs + (nb * 16 + ln) * LDP3 + ks * 32 + g * 8);
                acc[nb] = __builtin_amdgcn_mfma_f32_16x16x32_bf16(a, b, acc[nb], 0, 0, 0);
            }
        }
        __syncthreads();
    }

    #pragma unroll
    for (int nb = 0; nb < 4; ++nb) {
        int gn = bn + nb * 16 + ln;
        float bv = (bias && gn < N) ? bias[bnb + nb * 16 + ln] : 0.f;
        #pragma unroll
        for (int r = 0; r < 4; ++r) {
            int gm = bm + w * 16 + g * 4 + r;
            if (gm < M && gn < N) {
                float v = acc[nb][r] + bv;
                if (EPI == 1) v = (v >= 0.f) ? v : 0.2f * v;
                else if (EPI == 2) v = 1.f / (1.f + expf(-v));
                if (Cf) Cf[(size_t)gm * ldc + gn] = v;
                if (Cb) Cb[(size_t)gm * ldcb + gn] = f2bf(v);
                if (Ct && gn >= nsplitT)
                    Ct[(size_t)(gn - nsplitT) * ldct + gm] = f2bf(v);
            }
        }
    }
}

// ---------------------------------------------------------------------------
#define WP 168
#define TP 24
#define WTR 217
#define WROWS 208
#define APAD 256
#define BIGN (1 << 30)

// fused: blocks 0..767 = doc l1 partial sums; blocks 768+ = conv-W/adj prep
__global__ void prepdoc_k(const float* __restrict__ doc, float* __restrict__ dpart,
                          const float* __restrict__ cw, const float* __restrict__ cb,
                          const float* __restrict__ adj,
                          short* __restrict__ wkg, short* __restrict__ adj_bf)
{
    if (blockIdx.x < 768) {
        int u = blockIdx.x;
        int dc = u % 12, sc = (u / 12) % 8, b = u / 96;
        int dx = threadIdx.x & 63, sy = threadIdx.x >> 6;
        int d = dc * 64 + dx;
        const float* pp = doc + ((size_t)b * SS + sc * 64) * DD + d;
        float s = 0.f;
        for (int t = sy; t < 64; t += 4) s += fabsf(pp[(size_t)t * DD]);
        __shared__ float red[4][64];
        red[sy][dx] = s;
        __syncthreads();
        if (sy == 0)
            dpart[((size_t)b * 8 + sc) * DD + d] = red[0][dx] + red[1][dx] + red[2][dx] + red[3][dx];
        return;
    }
    int idx = (blockIdx.x - 768) * 256 + threadIdx.x;
    if (idx < WROWS * WP) {
        int o = idx / WP, kk = idx % WP;
        int kj = kk >> 4, ki = kk & 15;
        float v = 0.f;
        if (o < LL && kj < 9) {
            if (ki < 9) v = cw[o * 81 + ki * 9 + kj];
            else if (ki == 9 && kj == 0) v = cb[o];
        }
        wkg[idx] = f2bf(v);
        return;
    }
    idx -= WROWS * WP;
    if (idx < LL * APAD) {
        int r = idx / APAD, c = idx % APAD;
        adj_bf[idx] = f2bf(c < LL ? adj[r * LL + c] : 0.f);
    }
}

__global__ void docbfB_k(const float* __restrict__ doc, const float* __restrict__ dpart,
                         short* __restrict__ docb)
{
    int gid = blockIdx.x * blockDim.x + threadIdx.x;
    if (gid >= BB * SS * DD / 4) return;
    size_t base = (size_t)gid * 4;
    int d = (int)(base % DD);
    int b = (int)(base / ((size_t)SS * DD));
    float4 v = *(const float4*)(doc + base);
    float4 dn = {0.f, 0.f, 0.f, 0.f};
    #pragma unroll
    for (int sc = 0; sc < 8; ++sc) {
        float4 t = *(const float4*)(dpart + ((size_t)b * 8 + sc) * DD + d);
        dn.x += t.x; dn.y += t.y; dn.z += t.z; dn.w += t.w;
    }
    dn.x = fmaxf(dn.x, 1e-12f); dn.y = fmaxf(dn.y, 1e-12f);
    dn.z = fmaxf(dn.z, 1e-12f); dn.w = fmaxf(dn.w, 1e-12f);
    short4 o;
    o.x = f2bf(v.x / dn.x);
    o.y = f2bf(v.y / dn.y);
    o.z = f2bf(v.z / dn.z);
    o.w = f2bf(v.w / dn.w);
    *(short4*)(docb + base) = o;
}

// fused colsum + rsqrt + normalized adjacency
__global__ void ca_k(const float* __restrict__ A, short* __restrict__ An)
{
    int i = blockIdx.x;
    int j = threadIdx.x;
    float si = 0.f, sj = 0.f;
    for (int l = 0; l < LL; ++l) {
        si += A[l * LL + i];
        if (j < LL) sj += A[l * LL + j];
    }
    float di = (si > 0.f) ? (1.f / sqrtf(si)) : 0.f;
    float dj = (sj > 0.f) ? (1.f / sqrtf(sj)) : 0.f;
    float v = (j < LL) ? A[j * LL + i] * di * dj : 0.f;
    An[i * APAD + j] = f2bf(v);
}

// l1-normalize columns of X [L,D] over L, emit bf16
__global__ void l1n_k(const float* __restrict__ X, short* __restrict__ Xb)
{
    int c = threadIdx.x >> 5, r = threadIdx.x & 31;
    int col = blockIdx.x * 8 + c;
    float s = 0.f;
    for (int l = r; l < LL; l += 32) s += fabsf(X[l * DD + col]);
    #pragma unroll
    for (int off = 16; off > 0; off >>= 1) s += __shfl_xor(s, off, 64);
    float inv = 1.f / fmaxf(s, 1e-12f);
    for (int l = r; l < LL; l += 32)
        Xb[l * DD + col] = f2bf(X[l * DD + col] * inv);
}

// ---------------------------------------------------------------------------
// Conv v3: half-specialized blocks (R16-proven) + LDS-overlay wbf staging.
// Phase 1: stage 12x216 bf16 window into Wlh area (coalesced copies).
// Phase 2: build winT from LDS (no scalar global loads).
// Phase 3: stage W-half over the wbf area. Then compute.
// ---------------------------------------------------------------------------
template<int NS>
__device__ __forceinline__ void conv_body2(const short* __restrict__ Wlh,
                                           const short* __restrict__ WT,
                                           int lrow0, int soffG,
                                           int ln, int g, float& lm)
{
    bf16x8 Af[NS][5];
    #pragma unroll
    for (int s = 0; s < NS; ++s)
        #pragma unroll
        for (int j = 0; j < 5; ++j)
            Af[s][j] = *(const bf16x8*)(Wlh + (lrow0 + s * 16 + ln) * WP + j * 32 + g * 8);

    #pragma unroll 1
    for (int nt = 0; nt < 13; ++nt) {
        bf16x8 Bf[5];
        #pragma unroll
        for (int j = 0; j < 5; ++j)
            Bf[j] = *(const bf16x8*)(WT + (nt * 16 + ln + 2 * j + (g >> 1)) * TP + (g & 1) * 8);

        f32x4 acc[NS];
        #pragma unroll
        for (int s = 0; s < NS; ++s) acc[s] = (f32x4){0.f, 0.f, 0.f, 0.f};

        #pragma unroll
        for (int j = 0; j < 5; ++j)
            #pragma unroll
            for (int s = 0; s < NS; ++s)
                acc[s] = __builtin_amdgcn_mfma_f32_16x16x32_bf16(Af[s][j], Bf[j], acc[s], 0, 0, 0);

        bool colOK = (nt < 12) | (ln < 8);
        #pragma unroll
        for (int s = 0; s < NS; ++s) {
            float t = fmaxf(fmaxf(acc[s][0], acc[s][1]), fmaxf(acc[s][2], acc[s][3]));
            bool ok = colOK & ((soffG + s < 12) | (g < 2));   // o<200, l<200
            lm = ok ? fmaxf(lm, t) : lm;
        }
    }
}

__global__ __launch_bounds__(512, 2) void conv_max_k(
    const short* __restrict__ wlab,  // [4096, 200] bf16
    const short* __restrict__ wkg,   // [208][WP] bf16
    float* __restrict__ ghalf)       // [2][4096] partial max (pre-tanh)
{
    extern __shared__ short smem[];
    short* Wlh  = smem;                       // 112*168 = 18816 shorts
    short* winT = Wlh + 112 * WP;             // 4*217*24 = 20832 shorts
    short* wbf  = Wlh;                        // overlay: 12*216 = 2592 shorts
    __shared__ float wredf[8];

    const int blk = blockIdx.x;               // 2048
    const int h = blk & 1;
    const int sg = (blk >> 1) & 127;
    const int b = blk >> 8;
    const int s0 = sg << 2;
    const int tid = threadIdx.x;

    // phase 1: stage raw window rows s0-4..s0+7 (12), cols -4..211 (bf16 copy)
    for (int idx = tid; idx < 12 * 216; idx += 512) {
        int r = idx / 216, c = idx % 216;
        int sr = s0 - 4 + r, col = c - 4;
        short v = 0;
        if (sr >= 0 && sr < SS && col >= 0 && col < LL)
            v = wlab[((size_t)b * SS + sr) * LL + col];
        wbf[idx] = v;
    }
    __syncthreads();
    // phase 2: build per-position transposed windows from LDS (+ bias tap)
    for (int idx = tid; idx < 4 * WTR; idx += 512) {
        int p = idx / WTR, r = idx % WTR;
        short vals[16];
        #pragma unroll
        for (int i = 0; i < 9; ++i) vals[i] = (r < 216) ? wbf[(p + i) * 216 + r] : (short)0;
        vals[9] = (short)0x3F80;   // 1.0 bias tap
        #pragma unroll
        for (int i = 10; i < 16; ++i) vals[i] = 0;
        short* dstp = winT + (p * WTR + r) * TP;
        *(bf16x8*)dstp = *(const bf16x8*)vals;
        *(bf16x8*)(dstp + 8) = *(const bf16x8*)(vals + 8);
    }
    __syncthreads();
    // phase 3: stage this half's W rows over the wbf area
    {
        const int4* src = (const int4*)wkg;
        int4* dst = (int4*)Wlh;
        const int row0 = h * 112;
        for (int i = tid; i < 112 * 21; i += 512) {
            int r = i / 21, c = i % 21;
            int gr = row0 + r;
            int4 v = {0, 0, 0, 0};
            if (gr < WROWS) v = src[gr * 21 + c];
            dst[i] = v;
        }
    }
    __syncthreads();

    const int w = tid >> 6;        // wave 0..7
    const int p = w >> 1;          // position 0..3
    const int q = w & 1;           // strip subgroup
    const int lane = tid & 63;
    const int g = lane >> 4;
    const int ln = lane & 15;
    const short* WT = winT + p * WTR * TP;

    float lm = -INFINITY;
    if (h == 0) {
        if (q == 0) conv_body2<4>(Wlh, WT, 0,  0,  ln, g, lm);
        else        conv_body2<3>(Wlh, WT, 64, 4,  ln, g, lm);
    } else {
        if (q == 0) conv_body2<3>(Wlh, WT, 0,  7,  ln, g, lm);
        else        conv_body2<3>(Wlh, WT, 48, 10, ln, g, lm);
    }

    #pragma unroll
    for (int off = 32; off > 0; off >>= 1)
        lm = fmaxf(lm, __shfl_xor(lm, off, 64));
    if (lane == 0) wredf[w] = lm;
    __syncthreads();
    if (tid < 4)
        ghalf[(size_t)h * (BB * SS) + ((size_t)b << 9) + s0 + tid] =
            fmaxf(wredf[2 * tid], wredf[2 * tid + 1]);
}

// ---------------------------------------------------------------------------
// h_enc partials from bf16 doc_nb; gate = tanh(max(ghalf0, ghalf1))
// ---------------------------------------------------------------------------
__global__ void henc_part_k(const short* __restrict__ doc_nb, const float* __restrict__ ghalf,
                            float* __restrict__ hpart)
{
    int dc = blockIdx.x, sc = blockIdx.y, b = blockIdx.z;
    int dx = threadIdx.x & 63, sy = threadIdx.x >> 6;
    int d = dc * 64 + dx;
    __shared__ float gsh[64];
    __shared__ float red[4][64];
    if (threadIdx.x < 64) {
        int srow = sc * 64 + threadIdx.x;
        size_t bs = (size_t)b * SS + srow;
        gsh[threadIdx.x] = tanhf(fmaxf(ghalf[bs], ghalf[(size_t)BB * SS + bs]));
    }
    __syncthreads();
    float s = 0.f;
    for (int t = sy; t < 64; t += 4) {
        int srow = sc * 64 + t;
        s = fmaf(bf2f(doc_nb[((size_t)b * SS + srow) * DD + d]), gsh[t], s);
    }
    red[sy][dx] = s;
    __syncthreads();
    if (sy == 0)
        hpart[((size_t)b * 8 + sc) * DD + d] = red[0][dx] + red[1][dx] + red[2][dx] + red[3][dx];
}

// final: h, linear, sigmoid, per-block loss partial -> atomicAdd
__global__ void final3_k(const float* __restrict__ hpart,
                         const float* __restrict__ W, const float* __restrict__ bias,
                         const float* __restrict__ labels, float* __restrict__ out)
{
    int b = blockIdx.x, tid = threadIdx.x;
    __shared__ float hb[DD];
    __shared__ float ws4[4];
    for (int idx = tid; idx < DD; idx += 256) {
        float s = 0.f;
        #pragma unroll
        for (int sc = 0; sc < 8; ++sc) s += hpart[((size_t)b * 8 + sc) * DD + idx];
        hb[idx] = s;
    }
    __syncthreads();
    int l = tid;
    float term = 0.f;
    if (l < LL) {
        float acc = bias[l];
        for (int d = 0; d < DD; ++d) acc = fmaf(hb[d], W[d * LL + l], acc);
        float sig = 1.f / (1.f + expf(-acc));
        out[b * LL + l] = sig;
        float pp = fminf(fmaxf(sig, 1e-7f), 1.f - 1e-7f);
        float y = labels[b * LL + l];
        term = y * logf(pp) + (1.f - y) * logf(1.f - pp);
    }
    #pragma unroll
    for (int off = 32; off > 0; off >>= 1) term += __shfl_down(term, off, 64);
    if ((tid & 63) == 0) ws4[tid >> 6] = term;
    __syncthreads();
    if (tid == 0)
        atomicAdd(out + BB * LL, -(ws4[0] + ws4[1] + ws4[2] + ws4[3]) / (float)(BB * LL));
}

// ---------------------------------------------------------------------------
static void mgemm(hipStream_t st, int epi, bool tb,
                  const short* A, int lda, const void* B, int ldb,
                  const float* bias,
                  const void* B2, const float* bias2, int nsplit,
                  const void* B3, const float* bias3, int nsplit2,
                  float* Cf, int ldc, short* Cb, int ldcb,
                  short* Ct, int ldct, int nsplitT,
                  int M, int N, int K)
{
    dim3 g((N + 63) / 64, (M + 63) / 64);
    #define LAUNCH(E, T) do { \
        (void)hipFuncSetAttribute((const void*)mgemm_k<E, T>, \
                                  hipFuncAttributeMaxDynamicSharedMemorySize, MGLDS); \
        mgemm_k<E, T><<<g, 256, MGLDS, st>>>(A, lda, B, ldb, bias, B2, bias2, nsplit, \
                                             B3, bias3, nsplit2, Cf, ldc, Cb, ldcb, \
                                             Ct, ldct, nsplitT, M, N, K); \
    } while (0)
    if (!tb) {
        if (epi == 0)      LAUNCH(0, false);
        else if (epi == 1) LAUNCH(1, false);
        else               LAUNCH(2, false);
    } else {
        if (epi == 0)      LAUNCH(0, true);
        else if (epi == 1) LAUNCH(1, true);
        else               LAUNCH(2, true);
    }
    #undef LAUNCH
}

extern "C" void kernel_launch(void* const* d_in, const int* in_sizes, int n_in,
                              void* d_out, int out_size, void* d_ws, size_t ws_size,
                              hipStream_t stream)
{
    const float* doc_emb   = (const float*)d_in[0];
    const float* labels    = (const float*)d_in[1];
    const float* label_emb = (const float*)d_in[2];
    const float* label_adj = (const float*)d_in[3];
    const float* w_gcn3    = (const float*)d_in[4];
    const float* w_gcn5    = (const float*)d_in[5];
    const float* w_ll1     = (const float*)d_in[6];
    const float* b_ll1     = (const float*)d_in[7];
    const float* w_ll2     = (const float*)d_in[8];
    const float* b_ll2     = (const float*)d_in[9];
    const float* w_lin     = (const float*)d_in[10];
    const float* b_lin     = (const float*)d_in[11];
    const float* conv_w    = (const float*)d_in[12];
    const float* conv_b    = (const float*)d_in[13];
    const float* w_lin1    = (const float*)d_in[14];
    const float* b_lin1    = (const float*)d_in[15];

    float* out = (float*)d_out;   // [B*L] + [1]

    char* p = (char*)d_ws;
    auto alloc = [&](size_t bytes) { void* r = p; p += (bytes + 15) & ~(size_t)15; return r; };
    short* wkg       = (short*)alloc(WROWS * WP * 2);
    short* adj_bf    = (short*)alloc(200 * APAD * 2);
    short* E2_bf     = (short*)alloc(200 * 768 * 2);
    short* le_cat_bf = (short*)alloc(200 * 1536 * 2);   // [le | d_le]
    short* qkh_bf    = (short*)alloc(200 * 2304 * 2);   // [q | k | H]
    short* Ht        = (short*)alloc(768 * 256 * 2);    // H^T, K-pitch 256
    float* Amat      = (float*)alloc(200 * 200 * 4);
    short* Anorm_bf  = (short*)alloc(200 * APAD * 2);
    float* le_out_f  = (float*)alloc(200 * 768 * 4);
    short* le_out_bf = (short*)alloc(200 * 768 * 2);
    float* dpart     = (float*)alloc(BB * 8 * DD * 4);
    short* doc_nb    = (short*)alloc((size_t)BB * SS * DD * 2);
    short* wlab      = (short*)alloc((size_t)BB * SS * LL * 2);
    float* ghalf     = (float*)alloc(2 * BB * SS * 4);
    float* hpart     = (float*)alloc(BB * 8 * DD * 4);

    // zero the loss accumulator (graph-captured memset node)
    hipMemsetAsync(out + BB * LL, 0, 4, stream);

    // doc l1 partials + conv-W/adj prep (fused, independent work)
    prepdoc_k<<<768 + (WROWS * WP + LL * APAD + 255) / 256, 256, 0, stream>>>(
        doc_emb, dpart, conv_w, conv_b, label_adj, wkg, adj_bf);
    // doc l1 finalize -> bf16
    docbfB_k<<<(BB * SS * DD / 4 + 255) / 256, 256, 0, stream>>>(doc_emb, dpart, doc_nb);
    // E2 = adj @ emb   [200,768] K=200 (1 K-iter)
    mgemm(stream, 0, false, adj_bf, APAD, label_emb, DD, nullptr,
          nullptr, nullptr, BIGN, nullptr, nullptr, BIGN,
          nullptr, 0, E2_bf, DD, nullptr, 0, BIGN, LL, DD, LL);
    // le = leaky(E2 @ W3) -> bf16 le_cat[:, :768]  (3 K-iters)
    mgemm(stream, 1, false, E2_bf, DD, w_gcn3, DD, nullptr,
          nullptr, nullptr, BIGN, nullptr, nullptr, BIGN,
          nullptr, 0, le_cat_bf, 1536, nullptr, 0, BIGN, LL, DD, DD);
    // [q|k|H] = le @ [w_ll1|w_ll2|w_gcn5] + [b1|b2|0]  N=2304; H also -> Ht^T
    mgemm(stream, 0, false, le_cat_bf, 1536, w_ll1, DD, b_ll1,
          w_ll2, b_ll2, DD, w_gcn5, nullptr, 2 * DD,
          nullptr, 0, qkh_bf, 2304, Ht, 256, 2 * DD, LL, 3 * DD, DD);
    // A = sigmoid(q @ k^T)  [200,200] K=768 (3 K-iters)
    mgemm(stream, 2, true, qkh_bf, 2304, qkh_bf + DD, 2304, nullptr,
          nullptr, nullptr, BIGN, nullptr, nullptr, BIGN,
          Amat, LL, nullptr, 0, nullptr, 0, BIGN, LL, LL, DD);
    // fused colsum + rsqrt + normalized adjacency
    ca_k<<<LL, 256, 0, stream>>>(Amat, Anorm_bf);
    // d_le = leaky(Anorm @ H)  K=200 via Ht (1 K-iter) -> le_cat[:, 768:]
    mgemm(stream, 1, true, Anorm_bf, APAD, Ht, 256, nullptr,
          nullptr, nullptr, BIGN, nullptr, nullptr, BIGN,
          nullptr, 0, le_cat_bf + DD, 1536, nullptr, 0, BIGN, LL, DD, LL);
    // le_out = le_cat @ w_lin + b_lin   K=1536 (6 K-iters)
    mgemm(stream, 0, false, le_cat_bf, 1536, w_lin, DD, b_lin,
          nullptr, nullptr, BIGN, nullptr, nullptr, BIGN,
          le_out_f, DD, nullptr, 0, nullptr, 0, BIGN, LL, DD, 2 * DD);
    // l1 normalize over L -> bf16
    l1n_k<<<96, 256, 0, stream>>>(le_out_f, le_out_bf);
    // wla = doc_n @ le_out^T   [4096,200] K=768 -> bf16 output
    mgemm(stream, 0, true, doc_nb, DD, le_out_bf, DD, nullptr,
          nullptr, nullptr, BIGN, nullptr, nullptr, BIGN,
          nullptr, 0, wlab, LL, nullptr, 0, BIGN, BB * SS, LL, DD);
    // conv + max (v3: LDS-overlay staging, 2 blocks/CU)
    (void)hipFuncSetAttribute((const void*)conv_max_k,
                              hipFuncAttributeMaxDynamicSharedMemorySize, 79296);
    conv_max_k<<<2048, 512, 79296, stream>>>(wlab, wkg, ghalf);
    // h_enc partials (tanh(max) folded)
    henc_part_k<<<dim3(12, 8, 8), 256, 0, stream>>>(doc_nb, ghalf, hpart);
    // final linear + sigmoid + loss (fused)
    final3_k<<<BB, 256, 0, stream>>>(hpart, w_lin1, b_lin1, labels, out);
}

// Round 18
// 269.933 us; speedup vs baseline: 1.0114x; 1.0114x over previous
//
#include <hip/hip_runtime.h>
#include <hip/hip_bf16.h>
#include <math.h>

// Problem constants
#define BB 8
#define SS 512
#define DD 768
#define LL 200

typedef __attribute__((ext_vector_type(8))) short bf16x8;
typedef __attribute__((ext_vector_type(4))) float f32x4;

__device__ inline short f2bf(float f) {
    unsigned u = __builtin_bit_cast(unsigned, f);
    unsigned r = (u + 0x7FFFu + ((u >> 16) & 1u)) >> 16;
    return (short)r;
}
__device__ inline float bf2f(short s) {
    unsigned u = ((unsigned)(unsigned short)s) << 16;
    return __builtin_bit_cast(float, u);
}

// ---------------------------------------------------------------------------
// MFMA bf16 GEMM, BK=256 (R14..R17-verified)
// ---------------------------------------------------------------------------
#define LDP3 264   // LDS row pitch (528 B = 33*16B odd)
#define BK3  256
#define MGLDS (2 * 64 * LDP3 * 2)   // 67584 B dynamic

template<int EPI, bool TB>
__global__ __launch_bounds__(256, 1) void mgemm_k(
    const short* __restrict__ A, int lda,
    const void* __restrict__ Bv, int ldb,
    const float* __restrict__ bias,
    const void* __restrict__ Bv2, const float* __restrict__ bias2, int nsplit,
    const void* __restrict__ Bv3, const float* __restrict__ bias3, int nsplit2,
    float* __restrict__ Cf, int ldc,
    short* __restrict__ Cb, int ldcb,
    short* __restrict__ Ct, int ldct, int nsplitT,
    int M, int N, int K)
{
    extern __shared__ short dsm[];
    short* As = dsm;
    short* Bs = dsm + 64 * LDP3;
    const int tid = threadIdx.x;
    const int bm = blockIdx.y * 64;
    const int bn = blockIdx.x * 64;
    int bnb = bn;
    if (!TB) {
        if (bn >= nsplit2)      { Bv = Bv3; bias = bias3; bnb = bn - nsplit2; }
        else if (bn >= nsplit)  { Bv = Bv2; bias = bias2; bnb = bn - nsplit; }
    }
    const int w = tid >> 6, lane = tid & 63, g = lane >> 4, ln = lane & 15;
    const int Kp = (K + BK3 - 1) & ~(BK3 - 1);
    const int nt = Kp >> 8;

    const int ar = tid >> 2, ac = tid & 3;
    const int bn_ = tid & 63, bko = (tid >> 6) * 64;

    f32x4 acc[4];
    #pragma unroll
    for (int i = 0; i < 4; ++i) acc[i] = (f32x4){0.f, 0.f, 0.f, 0.f};

    bf16x8 aR[8], bT[8];
    #pragma unroll
    for (int j = 0; j < 8; ++j) { aR[j] = (bf16x8){0,0,0,0,0,0,0,0}; bT[j] = (bf16x8){0,0,0,0,0,0,0,0}; }
    float bF[64];
    #pragma unroll
    for (int j = 0; j < 64; ++j) bF[j] = 0.f;

    const int gmS = bm + ar;
    const bool aOk = (gmS < M);

    auto fetchA = [&](int k0) {
        if (aOk) {
            const short* p = A + (size_t)gmS * lda + k0 + ac * 64;
            #pragma unroll
            for (int j = 0; j < 8; ++j) aR[j] = *(const bf16x8*)(p + j * 8);
        }
    };
    auto fetchB = [&](int k0) {
        if (TB) {
            const short* Bt = (const short*)Bv;
            int gn = bn + ar;
            if (gn < N) {
                const short* p = Bt + (size_t)gn * ldb + k0 + ac * 64;
                #pragma unroll
                for (int j = 0; j < 8; ++j) bT[j] = *(const bf16x8*)(p + j * 8);
            }
        } else {
            const float* Bp = (const float*)Bv + (size_t)(bnb + bn_);
            #pragma unroll
            for (int j = 0; j < 64; ++j) {
                int gk = k0 + bko + j;
                bF[j] = (gk < K) ? Bp[(size_t)gk * ldb] : 0.f;
            }
        }
    };

    fetchA(0);
    fetchB(0);

    for (int t = 0; t < nt; ++t) {
        {
            short* pa = As + ar * LDP3 + ac * 64;
            #pragma unroll
            for (int j = 0; j < 8; ++j) *(bf16x8*)(pa + j * 8) = aR[j];
        }
        if (TB) {
            short* pb = Bs + ar * LDP3 + ac * 64;
            #pragma unroll
            for (int j = 0; j < 8; ++j) *(bf16x8*)(pb + j * 8) = bT[j];
        } else {
            short* pb = Bs + bn_ * LDP3 + bko;
            #pragma unroll
            for (int q = 0; q < 8; ++q) {
                bf16x8 v;
                #pragma unroll
                for (int e = 0; e < 8; ++e) v[e] = f2bf(bF[q * 8 + e]);
                *(bf16x8*)(pb + q * 8) = v;
            }
        }
        __syncthreads();

        if (t + 1 < nt) {
            int k0 = (t + 1) << 8;
            fetchA(k0);
            fetchB(k0);
        }

        #pragma unroll
        for (int ks = 0; ks < 8; ++ks) {
            bf16x8 a = *(const bf16x8*)(As + (w * 16 + ln) * LDP3 + ks * 32 + g * 8);
            #pragma unroll
            for (int nb = 0; nb < 4; ++nb) {
                bf16x8 b = *(const bf16x8*)(Bs + (nb * 16 + ln) * LDP3 + ks * 32 + g * 8);
                acc[nb] = __builtin_amdgcn_mfma_f32_16x16x32_bf16(a, b, acc[nb], 0, 0, 0);
            }
        }
        __syncthreads();
    }

    #pragma unroll
    for (int nb = 0; nb < 4; ++nb) {
        int gn = bn + nb * 16 + ln;
        float bv = (bias && gn < N) ? bias[bnb + nb * 16 + ln] : 0.f;
        #pragma unroll
        for (int r = 0; r < 4; ++r) {
            int gm = bm + w * 16 + g * 4 + r;
            if (gm < M && gn < N) {
                float v = acc[nb][r] + bv;
                if (EPI == 1) v = (v >= 0.f) ? v : 0.2f * v;
                else if (EPI == 2) v = 1.f / (1.f + expf(-v));
                if (Cf) Cf[(size_t)gm * ldc + gn] = v;
                if (Cb) Cb[(size_t)gm * ldcb + gn] = f2bf(v);
                if (Ct && gn >= nsplitT)
                    Ct[(size_t)(gn - nsplitT) * ldct + gm] = f2bf(v);
            }
        }
    }
}

// ---------------------------------------------------------------------------
#define WP 168
#define TP 24
#define WTR 217
#define WROWS 208
#define APAD 256
#define BIGN (1 << 30)

// fused: blocks 0..767 = doc l1 partial sums; blocks 768+ = conv-W/adj prep
__global__ void prepdoc_k(const float* __restrict__ doc, float* __restrict__ dpart,
                          const float* __restrict__ cw, const float* __restrict__ cb,
                          const float* __restrict__ adj,
                          short* __restrict__ wkg, short* __restrict__ adj_bf)
{
    if (blockIdx.x < 768) {
        int u = blockIdx.x;
        int dc = u % 12, sc = (u / 12) % 8, b = u / 96;
        int dx = threadIdx.x & 63, sy = threadIdx.x >> 6;
        int d = dc * 64 + dx;
        const float* pp = doc + ((size_t)b * SS + sc * 64) * DD + d;
        float s = 0.f;
        for (int t = sy; t < 64; t += 4) s += fabsf(pp[(size_t)t * DD]);
        __shared__ float red[4][64];
        red[sy][dx] = s;
        __syncthreads();
        if (sy == 0)
            dpart[((size_t)b * 8 + sc) * DD + d] = red[0][dx] + red[1][dx] + red[2][dx] + red[3][dx];
        return;
    }
    int idx = (blockIdx.x - 768) * 256 + threadIdx.x;
    if (idx < WROWS * WP) {
        int o = idx / WP, kk = idx % WP;
        int kj = kk >> 4, ki = kk & 15;
        float v = 0.f;
        if (o < LL && kj < 9) {
            if (ki < 9) v = cw[o * 81 + ki * 9 + kj];
            else if (ki == 9 && kj == 0) v = cb[o];
        }
        wkg[idx] = f2bf(v);
        return;
    }
    idx -= WROWS * WP;
    if (idx < LL * APAD) {
        int r = idx / APAD, c = idx % APAD;
        adj_bf[idx] = f2bf(c < LL ? adj[r * LL + c] : 0.f);
    }
}

__global__ void docbfB_k(const float* __restrict__ doc, const float* __restrict__ dpart,
                         short* __restrict__ docb)
{
    int gid = blockIdx.x * blockDim.x + threadIdx.x;
    if (gid >= BB * SS * DD / 4) return;
    size_t base = (size_t)gid * 4;
    int d = (int)(base % DD);
    int b = (int)(base / ((size_t)SS * DD));
    float4 v = *(const float4*)(doc + base);
    float4 dn = {0.f, 0.f, 0.f, 0.f};
    #pragma unroll
    for (int sc = 0; sc < 8; ++sc) {
        float4 t = *(const float4*)(dpart + ((size_t)b * 8 + sc) * DD + d);
        dn.x += t.x; dn.y += t.y; dn.z += t.z; dn.w += t.w;
    }
    dn.x = fmaxf(dn.x, 1e-12f); dn.y = fmaxf(dn.y, 1e-12f);
    dn.z = fmaxf(dn.z, 1e-12f); dn.w = fmaxf(dn.w, 1e-12f);
    short4 o;
    o.x = f2bf(v.x / dn.x);
    o.y = f2bf(v.y / dn.y);
    o.z = f2bf(v.z / dn.z);
    o.w = f2bf(v.w / dn.w);
    *(short4*)(docb + base) = o;
}

// fused colsum + rsqrt + normalized adjacency
__global__ void ca_k(const float* __restrict__ A, short* __restrict__ An)
{
    int i = blockIdx.x;
    int j = threadIdx.x;
    float si = 0.f, sj = 0.f;
    for (int l = 0; l < LL; ++l) {
        si += A[l * LL + i];
        if (j < LL) sj += A[l * LL + j];
    }
    float di = (si > 0.f) ? (1.f / sqrtf(si)) : 0.f;
    float dj = (sj > 0.f) ? (1.f / sqrtf(sj)) : 0.f;
    float v = (j < LL) ? A[j * LL + i] * di * dj : 0.f;
    An[i * APAD + j] = f2bf(v);
}

// l1-normalize columns of X [L,D] over L, emit bf16
__global__ void l1n_k(const float* __restrict__ X, short* __restrict__ Xb)
{
    int c = threadIdx.x >> 5, r = threadIdx.x & 31;
    int col = blockIdx.x * 8 + c;
    float s = 0.f;
    for (int l = r; l < LL; l += 32) s += fabsf(X[l * DD + col]);
    #pragma unroll
    for (int off = 16; off > 0; off >>= 1) s += __shfl_xor(s, off, 64);
    float inv = 1.f / fmaxf(s, 1e-12f);
    for (int l = r; l < LL; l += 32)
        Xb[l * DD + col] = f2bf(X[l * DD + col] * inv);
}

// ---------------------------------------------------------------------------
// Conv (R16 structure, bf16 input): half-specialized blocks, 2 blocks/CU,
// winT built directly from global bf16 wlab (L2-resident, no convert).
// ---------------------------------------------------------------------------
template<int NS>
__device__ __forceinline__ void conv_body2(const short* __restrict__ Wlh,
                                           const short* __restrict__ WT,
                                           int lrow0, int soffG,
                                           int ln, int g, float& lm)
{
    bf16x8 Af[NS][5];
    #pragma unroll
    for (int s = 0; s < NS; ++s)
        #pragma unroll
        for (int j = 0; j < 5; ++j)
            Af[s][j] = *(const bf16x8*)(Wlh + (lrow0 + s * 16 + ln) * WP + j * 32 + g * 8);

    #pragma unroll 1
    for (int nt = 0; nt < 13; ++nt) {
        bf16x8 Bf[5];
        #pragma unroll
        for (int j = 0; j < 5; ++j)
            Bf[j] = *(const bf16x8*)(WT + (nt * 16 + ln + 2 * j + (g >> 1)) * TP + (g & 1) * 8);

        f32x4 acc[NS];
        #pragma unroll
        for (int s = 0; s < NS; ++s) acc[s] = (f32x4){0.f, 0.f, 0.f, 0.f};

        #pragma unroll
        for (int j = 0; j < 5; ++j)
            #pragma unroll
            for (int s = 0; s < NS; ++s)
                acc[s] = __builtin_amdgcn_mfma_f32_16x16x32_bf16(Af[s][j], Bf[j], acc[s], 0, 0, 0);

        bool colOK = (nt < 12) | (ln < 8);
        #pragma unroll
        for (int s = 0; s < NS; ++s) {
            float t = fmaxf(fmaxf(acc[s][0], acc[s][1]), fmaxf(acc[s][2], acc[s][3]));
            bool ok = colOK & ((soffG + s < 12) | (g < 2));   // o<200, l<200
            lm = ok ? fmaxf(lm, t) : lm;
        }
    }
}

__global__ __launch_bounds__(512, 2) void conv_max_k(
    const short* __restrict__ wlab,  // [4096, 200] bf16
    const short* __restrict__ wkg,   // [208][WP] bf16
    float* __restrict__ ghalf)       // [2][4096] partial max (pre-tanh)
{
    extern __shared__ short smem[];
    short* Wlh  = smem;                       // 112*168 = 18816 shorts
    short* winT = Wlh + 112 * WP;             // 4*217*24 = 20832 shorts
    __shared__ float wredf[8];

    const int blk = blockIdx.x;               // 2048
    const int h = blk & 1;
    const int sg = (blk >> 1) & 127;
    const int b = blk >> 8;
    const int s0 = sg << 2;
    const int tid = threadIdx.x;

    // stage this half's W rows [h*112, h*112+112), zero-pad rows >= 208
    {
        const int4* src = (const int4*)wkg;
        int4* dst = (int4*)Wlh;
        const int row0 = h * 112;
        for (int i = tid; i < 112 * 21; i += 512) {
            int r = i / 21, c = i % 21;
            int gr = row0 + r;
            int4 v = {0, 0, 0, 0};
            if (gr < WROWS) v = src[gr * 21 + c];
            dst[i] = v;
        }
    }
    // build per-position transposed windows directly from bf16 wlab (+ bias tap)
    for (int idx = tid; idx < 4 * WTR; idx += 512) {
        int p = idx / WTR, r = idx % WTR;
        int col = r - 4;
        short vals[16];
        #pragma unroll
        for (int i = 0; i < 9; ++i) {
            int srow = s0 + p - 4 + i;
            short v = 0;
            if (srow >= 0 && srow < SS && col >= 0 && col < LL)
                v = wlab[((size_t)b * SS + srow) * LL + col];
            vals[i] = v;
        }
        vals[9] = (short)0x3F80;   // 1.0 bias tap
        #pragma unroll
        for (int i = 10; i < 16; ++i) vals[i] = 0;
        short* dstp = winT + (p * WTR + r) * TP;
        *(bf16x8*)dstp = *(const bf16x8*)vals;
        *(bf16x8*)(dstp + 8) = *(const bf16x8*)(vals + 8);
    }
    __syncthreads();

    const int w = tid >> 6;        // wave 0..7
    const int p = w >> 1;          // position 0..3
    const int q = w & 1;           // strip subgroup
    const int lane = tid & 63;
    const int g = lane >> 4;
    const int ln = lane & 15;
    const short* WT = winT + p * WTR * TP;

    float lm = -INFINITY;
    if (h == 0) {
        if (q == 0) conv_body2<4>(Wlh, WT, 0,  0,  ln, g, lm);
        else        conv_body2<3>(Wlh, WT, 64, 4,  ln, g, lm);
    } else {
        if (q == 0) conv_body2<3>(Wlh, WT, 0,  7,  ln, g, lm);
        else        conv_body2<3>(Wlh, WT, 48, 10, ln, g, lm);
    }

    #pragma unroll
    for (int off = 32; off > 0; off >>= 1)
        lm = fmaxf(lm, __shfl_xor(lm, off, 64));
    if (lane == 0) wredf[w] = lm;
    __syncthreads();
    if (tid < 4)
        ghalf[(size_t)h * (BB * SS) + ((size_t)b << 9) + s0 + tid] =
            fmaxf(wredf[2 * tid], wredf[2 * tid + 1]);
}

// ---------------------------------------------------------------------------
// h_enc partials from bf16 doc_nb; gate = tanh(max(ghalf0, ghalf1))
// ---------------------------------------------------------------------------
__global__ void henc_part_k(const short* __restrict__ doc_nb, const float* __restrict__ ghalf,
                            float* __restrict__ hpart)
{
    int dc = blockIdx.x, sc = blockIdx.y, b = blockIdx.z;
    int dx = threadIdx.x & 63, sy = threadIdx.x >> 6;
    int d = dc * 64 + dx;
    __shared__ float gsh[64];
    __shared__ float red[4][64];
    if (threadIdx.x < 64) {
        int srow = sc * 64 + threadIdx.x;
        size_t bs = (size_t)b * SS + srow;
        gsh[threadIdx.x] = tanhf(fmaxf(ghalf[bs], ghalf[(size_t)BB * SS + bs]));
    }
    __syncthreads();
    float s = 0.f;
    for (int t = sy; t < 64; t += 4) {
        int srow = sc * 64 + t;
        s = fmaf(bf2f(doc_nb[((size_t)b * SS + srow) * DD + d]), gsh[t], s);
    }
    red[sy][dx] = s;
    __syncthreads();
    if (sy == 0)
        hpart[((size_t)b * 8 + sc) * DD + d] = red[0][dx] + red[1][dx] + red[2][dx] + red[3][dx];
}

// final: h, linear, sigmoid, per-block loss partial -> atomicAdd
__global__ void final3_k(const float* __restrict__ hpart,
                         const float* __restrict__ W, const float* __restrict__ bias,
                         const float* __restrict__ labels, float* __restrict__ out)
{
    int b = blockIdx.x, tid = threadIdx.x;
    __shared__ float hb[DD];
    __shared__ float ws4[4];
    for (int idx = tid; idx < DD; idx += 256) {
        float s = 0.f;
        #pragma unroll
        for (int sc = 0; sc < 8; ++sc) s += hpart[((size_t)b * 8 + sc) * DD + idx];
        hb[idx] = s;
    }
    __syncthreads();
    int l = tid;
    float term = 0.f;
    if (l < LL) {
        float acc = bias[l];
        for (int d = 0; d < DD; ++d) acc = fmaf(hb[d], W[d * LL + l], acc);
        float sig = 1.f / (1.f + expf(-acc));
        out[b * LL + l] = sig;
        float pp = fminf(fmaxf(sig, 1e-7f), 1.f - 1e-7f);
        float y = labels[b * LL + l];
        term = y * logf(pp) + (1.f - y) * logf(1.f - pp);
    }
    #pragma unroll
    for (int off = 32; off > 0; off >>= 1) term += __shfl_down(term, off, 64);
    if ((tid & 63) == 0) ws4[tid >> 6] = term;
    __syncthreads();
    if (tid == 0)
        atomicAdd(out + BB * LL, -(ws4[0] + ws4[1] + ws4[2] + ws4[3]) / (float)(BB * LL));
}

// ---------------------------------------------------------------------------
static void mgemm(hipStream_t st, int epi, bool tb,
                  const short* A, int lda, const void* B, int ldb,
                  const float* bias,
                  const void* B2, const float* bias2, int nsplit,
                  const void* B3, const float* bias3, int nsplit2,
                  float* Cf, int ldc, short* Cb, int ldcb,
                  short* Ct, int ldct, int nsplitT,
                  int M, int N, int K)
{
    dim3 g((N + 63) / 64, (M + 63) / 64);
    #define LAUNCH(E, T) do { \
        (void)hipFuncSetAttribute((const void*)mgemm_k<E, T>, \
                                  hipFuncAttributeMaxDynamicSharedMemorySize, MGLDS); \
        mgemm_k<E, T><<<g, 256, MGLDS, st>>>(A, lda, B, ldb, bias, B2, bias2, nsplit, \
                                             B3, bias3, nsplit2, Cf, ldc, Cb, ldcb, \
                                             Ct, ldct, nsplitT, M, N, K); \
    } while (0)
    if (!tb) {
        if (epi == 0)      LAUNCH(0, false);
        else if (epi == 1) LAUNCH(1, false);
        else               LAUNCH(2, false);
    } else {
        if (epi == 0)      LAUNCH(0, true);
        else if (epi == 1) LAUNCH(1, true);
        else               LAUNCH(2, true);
    }
    #undef LAUNCH
}

extern "C" void kernel_launch(void* const* d_in, const int* in_sizes, int n_in,
                              void* d_out, int out_size, void* d_ws, size_t ws_size,
                              hipStream_t stream)
{
    const float* doc_emb   = (const float*)d_in[0];
    const float* labels    = (const float*)d_in[1];
    const float* label_emb = (const float*)d_in[2];
    const float* label_adj = (const float*)d_in[3];
    const float* w_gcn3    = (const float*)d_in[4];
    const float* w_gcn5    = (const float*)d_in[5];
    const float* w_ll1     = (const float*)d_in[6];
    const float* b_ll1     = (const float*)d_in[7];
    const float* w_ll2     = (const float*)d_in[8];
    const float* b_ll2     = (const float*)d_in[9];
    const float* w_lin     = (const float*)d_in[10];
    const float* b_lin     = (const float*)d_in[11];
    const float* conv_w    = (const float*)d_in[12];
    const float* conv_b    = (const float*)d_in[13];
    const float* w_lin1    = (const float*)d_in[14];
    const float* b_lin1    = (const float*)d_in[15];

    float* out = (float*)d_out;   // [B*L] + [1]

    char* p = (char*)d_ws;
    auto alloc = [&](size_t bytes) { void* r = p; p += (bytes + 15) & ~(size_t)15; return r; };
    short* wkg       = (short*)alloc(WROWS * WP * 2);
    short* adj_bf    = (short*)alloc(200 * APAD * 2);
    short* E2_bf     = (short*)alloc(200 * 768 * 2);
    short* le_cat_bf = (short*)alloc(200 * 1536 * 2);   // [le | d_le]
    short* qkh_bf    = (short*)alloc(200 * 2304 * 2);   // [q | k | H]
    short* Ht        = (short*)alloc(768 * 256 * 2);    // H^T, K-pitch 256
    float* Amat      = (float*)alloc(200 * 200 * 4);
    short* Anorm_bf  = (short*)alloc(200 * APAD * 2);
    float* le_out_f  = (float*)alloc(200 * 768 * 4);
    short* le_out_bf = (short*)alloc(200 * 768 * 2);
    float* dpart     = (float*)alloc(BB * 8 * DD * 4);
    short* doc_nb    = (short*)alloc((size_t)BB * SS * DD * 2);
    short* wlab      = (short*)alloc((size_t)BB * SS * LL * 2);
    float* ghalf     = (float*)alloc(2 * BB * SS * 4);
    float* hpart     = (float*)alloc(BB * 8 * DD * 4);

    // zero the loss accumulator (graph-captured memset node)
    hipMemsetAsync(out + BB * LL, 0, 4, stream);

    // doc l1 partials + conv-W/adj prep (fused, independent work)
    prepdoc_k<<<768 + (WROWS * WP + LL * APAD + 255) / 256, 256, 0, stream>>>(
        doc_emb, dpart, conv_w, conv_b, label_adj, wkg, adj_bf);
    // doc l1 finalize -> bf16
    docbfB_k<<<(BB * SS * DD / 4 + 255) / 256, 256, 0, stream>>>(doc_emb, dpart, doc_nb);
    // E2 = adj @ emb   [200,768] K=200 (1 K-iter)
    mgemm(stream, 0, false, adj_bf, APAD, label_emb, DD, nullptr,
          nullptr, nullptr, BIGN, nullptr, nullptr, BIGN,
          nullptr, 0, E2_bf, DD, nullptr, 0, BIGN, LL, DD, LL);
    // le = leaky(E2 @ W3) -> bf16 le_cat[:, :768]  (3 K-iters)
    mgemm(stream, 1, false, E2_bf, DD, w_gcn3, DD, nullptr,
          nullptr, nullptr, BIGN, nullptr, nullptr, BIGN,
          nullptr, 0, le_cat_bf, 1536, nullptr, 0, BIGN, LL, DD, DD);
    // [q|k|H] = le @ [w_ll1|w_ll2|w_gcn5] + [b1|b2|0]  N=2304; H also -> Ht^T
    mgemm(stream, 0, false, le_cat_bf, 1536, w_ll1, DD, b_ll1,
          w_ll2, b_ll2, DD, w_gcn5, nullptr, 2 * DD,
          nullptr, 0, qkh_bf, 2304, Ht, 256, 2 * DD, LL, 3 * DD, DD);
    // A = sigmoid(q @ k^T)  [200,200] K=768 (3 K-iters)
    mgemm(stream, 2, true, qkh_bf, 2304, qkh_bf + DD, 2304, nullptr,
          nullptr, nullptr, BIGN, nullptr, nullptr, BIGN,
          Amat, LL, nullptr, 0, nullptr, 0, BIGN, LL, LL, DD);
    // fused colsum + rsqrt + normalized adjacency
    ca_k<<<LL, 256, 0, stream>>>(Amat, Anorm_bf);
    // d_le = leaky(Anorm @ H)  K=200 via Ht (1 K-iter) -> le_cat[:, 768:]
    mgemm(stream, 1, true, Anorm_bf, APAD, Ht, 256, nullptr,
          nullptr, nullptr, BIGN, nullptr, nullptr, BIGN,
          nullptr, 0, le_cat_bf + DD, 1536, nullptr, 0, BIGN, LL, DD, LL);
    // le_out = le_cat @ w_lin + b_lin   K=1536 (6 K-iters)
    mgemm(stream, 0, false, le_cat_bf, 1536, w_lin, DD, b_lin,
          nullptr, nullptr, BIGN, nullptr, nullptr, BIGN,
          le_out_f, DD, nullptr, 0, nullptr, 0, BIGN, LL, DD, 2 * DD);
    // l1 normalize over L -> bf16
    l1n_k<<<96, 256, 0, stream>>>(le_out_f, le_out_bf);
    // wla = doc_n @ le_out^T   [4096,200] K=768 -> bf16 output
    mgemm(stream, 0, true, doc_nb, DD, le_out_bf, DD, nullptr,
          nullptr, nullptr, BIGN, nullptr, nullptr, BIGN,
          nullptr, 0, wlab, LL, nullptr, 0, BIGN, BB * SS, LL, DD);
    // conv + max (R16 structure, bf16 input, 2 blocks/CU)
    (void)hipFuncSetAttribute((const void*)conv_max_k,
                              hipFuncAttributeMaxDynamicSharedMemorySize, 79296);
    conv_max_k<<<2048, 512, 79296, stream>>>(wlab, wkg, ghalf);
    // h_enc partials (tanh(max) folded)
    henc_part_k<<<dim3(12, 8, 8), 256, 0, stream>>>(doc_nb, ghalf, hpart);
    // final linear + sigmoid + loss (fused)
    final3_k<<<BB, 256, 0, stream>>>(hpart, w_lin1, b_lin1, labels, out);
}